// Round 1
// baseline (5451.780 us; speedup 1.0000x reference)
//
#include <hip/hip_runtime.h>
#include <hip/hip_bf16.h>
#include <math.h>

#define S_LEN 1024
#define HDIM  4096
#define NH    32
#define NKV   8
#define DH    128
#define NE    8
#define IM    1280

#define BM 64
#define BN 64
#define BK 16

// ---------------- RMSNorm ----------------
__global__ __launch_bounds__(256) void rmsnorm_k(const float* __restrict__ x,
                                                 const float* __restrict__ w,
                                                 float* __restrict__ o) {
  int s = blockIdx.x, tid = threadIdx.x;
  const float* xr = x + (size_t)s * HDIM;
  float ss = 0.f;
  for (int i = tid; i < HDIM; i += 256) { float v = xr[i]; ss += v * v; }
  __shared__ float red[256];
  red[tid] = ss; __syncthreads();
  for (int off = 128; off > 0; off >>= 1) {
    if (tid < off) red[tid] += red[tid + off];
    __syncthreads();
  }
  float inv = rsqrtf(red[0] / (float)HDIM + 1e-5f);
  float* orow = o + (size_t)s * HDIM;
  for (int i = tid; i < HDIM; i += 256) orow[i] = xr[i] * inv * w[i];
}

// ---------------- fp32 GEMM: C[M,N] = A[M,K] @ B[K,N] (+ R) ----------------
// grid = (N/64, M/64); M,N multiples of 64, K multiple of 16.
__global__ __launch_bounds__(256) void gemm_f32(const float* __restrict__ A,
                                                const float* __restrict__ B,
                                                float* __restrict__ C,
                                                const float* __restrict__ R,
                                                int N, int K) {
  alignas(16) __shared__ float As[BK][BM + 1];
  alignas(16) __shared__ float Bs[BK][BN];
  int tid = threadIdx.x;
  int bm = blockIdx.y * BM, bn = blockIdx.x * BN;
  int ty = tid >> 4, tx = tid & 15;
  int a_m = tid >> 2, a_k = (tid & 3) * 4;
  int b_k = tid >> 4, b_n = (tid & 15) * 4;
  float acc[4][4] = {};
  const float* Ap = A + (size_t)(bm + a_m) * K + a_k;
  const float* Bp = B + (size_t)b_k * N + bn + b_n;
  for (int k0 = 0; k0 < K; k0 += BK) {
    float4 av = *(const float4*)(Ap + k0);
    float4 bv = *(const float4*)(Bp + (size_t)k0 * N);
    As[a_k + 0][a_m] = av.x;
    As[a_k + 1][a_m] = av.y;
    As[a_k + 2][a_m] = av.z;
    As[a_k + 3][a_m] = av.w;
    *(float4*)&Bs[b_k][b_n] = bv;
    __syncthreads();
#pragma unroll
    for (int kk = 0; kk < BK; ++kk) {
      float4 b4 = *(const float4*)&Bs[kk][tx * 4];
#pragma unroll
      for (int i = 0; i < 4; ++i) {
        float a = As[kk][ty * 4 + i];
        acc[i][0] += a * b4.x; acc[i][1] += a * b4.y;
        acc[i][2] += a * b4.z; acc[i][3] += a * b4.w;
      }
    }
    __syncthreads();
  }
#pragma unroll
  for (int i = 0; i < 4; ++i) {
    int row = bm + ty * 4 + i;
#pragma unroll
    for (int j = 0; j < 4; ++j) {
      int col = bn + tx * 4 + j;
      float v = acc[i][j];
      if (R) v += R[(size_t)row * N + col];
      C[(size_t)row * N + col] = v;
    }
  }
}

// ---------------- YaRN cos/sin tables ----------------
__global__ void yarn_tables_k(const int* __restrict__ pos_ids,
                              float* __restrict__ cos_t, float* __restrict__ sin_t) {
  int s = blockIdx.x, d = threadIdx.x;  // d in [0,64)
  const double TWO_PI = 6.283185307179586476925286766559;
  double inv = pow(1.0e6, -((double)(2 * d)) / 128.0);
  double lnb = log(1.0e6);
  double low = floor(64.0 * log(65536.0 / (32.0 * TWO_PI)) / lnb);
  if (low < 0.0) low = 0.0;
  double high = ceil(64.0 * log(65536.0 / (1.0 * TWO_PI)) / lnb);
  if (high > 127.0) high = 127.0;
  double ramp = ((double)d - low) / (high - low);
  ramp = fmin(fmax(ramp, 0.0), 1.0);
  double extra = 1.0 - ramp;
  double inv_y = (inv / 2.0) * (1.0 - extra) + inv * extra;
  float invf = (float)inv_y;
  float p = (float)pos_ids[s];
  float ang = p * invf;                      // fp32 product, like reference
  const float scal = 1.0693147180559945f;    // 0.1*ln(2)+1
  cos_t[s * 64 + d] = cosf(ang) * scal;
  sin_t[s * 64 + d] = sinf(ang) * scal;
}

// ---------------- RoPE (in place on Q,K) ----------------
__global__ __launch_bounds__(256) void rope_k(float* __restrict__ Q, float* __restrict__ Kp,
                                              const float* __restrict__ cos_t,
                                              const float* __restrict__ sin_t) {
  int s = blockIdx.x, tid = threadIdx.x;
  const float* ct = cos_t + (size_t)s * 64;
  const float* st = sin_t + (size_t)s * 64;
  for (int i = tid; i < NH * 64; i += 256) {
    int h = i >> 6, d = i & 63;
    float* base = Q + (size_t)s * HDIM + h * DH;
    float q1 = base[d], q2 = base[d + 64];
    float c = ct[d], sn = st[d];
    base[d] = q1 * c - q2 * sn;
    base[d + 64] = q2 * c + q1 * sn;
  }
  for (int i = tid; i < NKV * 64; i += 256) {
    int h = i >> 6, d = i & 63;
    float* base = Kp + (size_t)s * (NKV * DH) + h * DH;
    float q1 = base[d], q2 = base[d + 64];
    float c = ct[d], sn = st[d];
    base[d] = q1 * c - q2 * sn;
    base[d + 64] = q2 * c + q1 * sn;
  }
}

// ---------------- attention: one block per (q, head), causal ----------------
__global__ __launch_bounds__(256) void attn_k(const float* __restrict__ Q,
                                              const float* __restrict__ Kb,
                                              const float* __restrict__ Vb,
                                              float* __restrict__ O) {
  int q = blockIdx.x, h = blockIdx.y, kvh = h >> 2;
  int tid = threadIdx.x;
  alignas(16) __shared__ float qs[DH];
  __shared__ float sc[S_LEN];
  __shared__ float red[256];
  if (tid < DH) qs[tid] = Q[(size_t)q * HDIM + h * DH + tid];
  __syncthreads();
  int kend = q + 1;
  const float scale = 0.08838834764831845f;  // 1/sqrt(128)
  const float4* qs4 = (const float4*)qs;
  for (int k = tid; k < kend; k += 256) {
    const float4* kr = (const float4*)(Kb + (size_t)k * (NKV * DH) + kvh * DH);
    float s = 0.f;
#pragma unroll 8
    for (int d = 0; d < DH / 4; ++d) {
      float4 a = qs4[d], b = kr[d];
      s += a.x * b.x + a.y * b.y + a.z * b.z + a.w * b.w;
    }
    sc[k] = s * scale;
  }
  float m = -3.0e38f;
  for (int k = tid; k < kend; k += 256) m = fmaxf(m, sc[k]);
  red[tid] = m; __syncthreads();
  for (int off = 128; off > 0; off >>= 1) {
    if (tid < off) red[tid] = fmaxf(red[tid], red[tid + off]);
    __syncthreads();
  }
  m = red[0];
  __syncthreads();
  float lsum = 0.f;
  for (int k = tid; k < kend; k += 256) {
    float e = expf(sc[k] - m);
    sc[k] = e; lsum += e;
  }
  red[tid] = lsum; __syncthreads();
  for (int off = 128; off > 0; off >>= 1) {
    if (tid < off) red[tid] += red[tid + off];
    __syncthreads();
  }
  float inv = 1.f / red[0];
  int d = tid & (DH - 1);
  int hlf = tid >> 7;
  float accv = 0.f;
  for (int k = hlf; k < kend; k += 2)
    accv += sc[k] * Vb[(size_t)k * (NKV * DH) + kvh * DH + d];
  __syncthreads();
  red[tid] = accv; __syncthreads();
  if (tid < DH)
    O[(size_t)q * HDIM + h * DH + tid] = (red[tid] + red[tid + 128]) * inv;
}

// ---------------- router: logits, sigmoid, top-2, normalized weights ----------------
__global__ __launch_bounds__(256) void router_k(const float* __restrict__ T,
                                                const float* __restrict__ wr,
                                                const float* __restrict__ eb,
                                                int* __restrict__ sel,
                                                float* __restrict__ selw) {
  int s = blockIdx.x, tid = threadIdx.x;
  int e = tid & 7, c = tid >> 3;  // 32 chunks of 128
  const float* tr = T + (size_t)s * HDIM;
  float p = 0.f;
  for (int hh = c * 128; hh < (c + 1) * 128; ++hh) p += tr[hh] * wr[hh * NE + e];
  __shared__ float red[256];
  red[tid] = p; __syncthreads();
  for (int off = 128; off >= 8; off >>= 1) {
    if (tid < off) red[tid] += red[tid + off];
    __syncthreads();
  }
  if (tid == 0) {
    float sg[NE], bb[NE];
    for (int i = 0; i < NE; ++i) { sg[i] = 1.f / (1.f + expf(-red[i])); bb[i] = sg[i] + eb[i]; }
    int i0 = 0;
    for (int i = 1; i < NE; ++i) if (bb[i] > bb[i0]) i0 = i;
    int i1 = -1;
    for (int i = 0; i < NE; ++i) if (i != i0 && (i1 < 0 || bb[i] > bb[i1])) i1 = i;
    float w0 = sg[i0], w1 = sg[i1], ws = w0 + w1;
    sel[s * 2] = i0; sel[s * 2 + 1] = i1;
    selw[s * 2] = w0 / ws; selw[s * 2 + 1] = w1 / ws;
  }
}

// ---------------- group (token,slot) pairs by expert ----------------
__global__ __launch_bounds__(1024) void group_k(const int* __restrict__ sel,
                                                const float* __restrict__ selw,
                                                int* __restrict__ offs,
                                                int* __restrict__ ptok,
                                                float* __restrict__ pw) {
  __shared__ int cnt[NE], base[NE], cur[NE];
  int t = threadIdx.x;  // token
  if (t < NE) { cnt[t] = 0; cur[t] = 0; }
  __syncthreads();
  int e0 = sel[t * 2], e1 = sel[t * 2 + 1];
  atomicAdd(&cnt[e0], 1); atomicAdd(&cnt[e1], 1);
  __syncthreads();
  if (t == 0) {
    int a = 0;
    for (int e = 0; e < NE; ++e) { base[e] = a; offs[e] = a; a += cnt[e]; }
    offs[NE] = a;
  }
  __syncthreads();
  int p0 = base[e0] + atomicAdd(&cur[e0], 1);
  ptok[p0] = t; pw[p0] = selw[t * 2];
  int p1 = base[e1] + atomicAdd(&cur[e1], 1);
  ptok[p1] = t; pw[p1] = selw[t * 2 + 1];
}

// ---------------- grouped GEMM (gate/up): C[r,0:IM] = T[tok[r]] @ W_e ----------------
// grid = (IM/64, 16, NE)
__global__ __launch_bounds__(256) void gemm_grouped_in(const float* __restrict__ T,
                                                       const float* __restrict__ W,
                                                       const int* __restrict__ offs,
                                                       const int* __restrict__ ptok,
                                                       float* __restrict__ C) {
  int e = blockIdx.z;
  int s0 = offs[e], s1 = offs[e + 1];
  int bm = s0 + blockIdx.y * BM;
  if (bm >= s1) return;
  int bn = blockIdx.x * BN;
  const float* B = W + (size_t)e * HDIM * IM;
  alignas(16) __shared__ float As[BK][BM + 1];
  alignas(16) __shared__ float Bs[BK][BN];
  int tid = threadIdx.x;
  int ty = tid >> 4, tx = tid & 15;
  int a_m = tid >> 2, a_k = (tid & 3) * 4;
  int b_k = tid >> 4, b_n = (tid & 15) * 4;
  int arow = bm + a_m;
  const float* Ap = (arow < s1) ? (T + (size_t)ptok[arow] * HDIM + a_k) : nullptr;
  const float* Bp = B + (size_t)b_k * IM + bn + b_n;
  float acc[4][4] = {};
  for (int k0 = 0; k0 < HDIM; k0 += BK) {
    float4 av = make_float4(0.f, 0.f, 0.f, 0.f);
    if (Ap) av = *(const float4*)(Ap + k0);
    float4 bv = *(const float4*)(Bp + (size_t)k0 * IM);
    As[a_k + 0][a_m] = av.x;
    As[a_k + 1][a_m] = av.y;
    As[a_k + 2][a_m] = av.z;
    As[a_k + 3][a_m] = av.w;
    *(float4*)&Bs[b_k][b_n] = bv;
    __syncthreads();
#pragma unroll
    for (int kk = 0; kk < BK; ++kk) {
      float4 b4 = *(const float4*)&Bs[kk][tx * 4];
#pragma unroll
      for (int i = 0; i < 4; ++i) {
        float a = As[kk][ty * 4 + i];
        acc[i][0] += a * b4.x; acc[i][1] += a * b4.y;
        acc[i][2] += a * b4.z; acc[i][3] += a * b4.w;
      }
    }
    __syncthreads();
  }
#pragma unroll
  for (int i = 0; i < 4; ++i) {
    int r = bm + ty * 4 + i;
    if (r < s1) {
#pragma unroll
      for (int j = 0; j < 4; ++j)
        C[(size_t)r * IM + bn + tx * 4 + j] = acc[i][j];
    }
  }
}

// ---------------- silu(g)*u*(weight) ----------------
__global__ __launch_bounds__(256) void act_mul_k(const float* __restrict__ g,
                                                 const float* __restrict__ u,
                                                 const float* __restrict__ pw,
                                                 float* __restrict__ a) {
  int r = blockIdx.x, tid = threadIdx.x;
  float wgt = pw ? pw[r] : 1.f;
  size_t bse = (size_t)r * IM;
  for (int i = tid; i < IM; i += 256) {
    float gv = g[bse + i], uv = u[bse + i];
    float sv = gv / (1.f + expf(-gv));
    a[bse + i] = sv * uv * wgt;
  }
}

// ---------------- grouped down GEMM: out[tok[r]] += act[r] @ Wd_e ----------------
// grid = (HDIM/64, 16, NE)
__global__ __launch_bounds__(256) void gemm_grouped_down(const float* __restrict__ Aact,
                                                         const float* __restrict__ W,
                                                         const int* __restrict__ offs,
                                                         const int* __restrict__ ptok,
                                                         float* __restrict__ Cout) {
  int e = blockIdx.z;
  int s0 = offs[e], s1 = offs[e + 1];
  int bm = s0 + blockIdx.y * BM;
  if (bm >= s1) return;
  int bn = blockIdx.x * BN;
  const float* B = W + (size_t)e * IM * HDIM;
  alignas(16) __shared__ float As[BK][BM + 1];
  alignas(16) __shared__ float Bs[BK][BN];
  int tid = threadIdx.x;
  int ty = tid >> 4, tx = tid & 15;
  int a_m = tid >> 2, a_k = (tid & 3) * 4;
  int b_k = tid >> 4, b_n = (tid & 15) * 4;
  int arow = bm + a_m;
  const float* Ap = (arow < s1) ? (Aact + (size_t)arow * IM + a_k) : nullptr;
  const float* Bp = B + (size_t)b_k * HDIM + bn + b_n;
  float acc[4][4] = {};
  for (int k0 = 0; k0 < IM; k0 += BK) {
    float4 av = make_float4(0.f, 0.f, 0.f, 0.f);
    if (Ap) av = *(const float4*)(Ap + k0);
    float4 bv = *(const float4*)(Bp + (size_t)k0 * HDIM);
    As[a_k + 0][a_m] = av.x;
    As[a_k + 1][a_m] = av.y;
    As[a_k + 2][a_m] = av.z;
    As[a_k + 3][a_m] = av.w;
    *(float4*)&Bs[b_k][b_n] = bv;
    __syncthreads();
#pragma unroll
    for (int kk = 0; kk < BK; ++kk) {
      float4 b4 = *(const float4*)&Bs[kk][tx * 4];
#pragma unroll
      for (int i = 0; i < 4; ++i) {
        float a = As[kk][ty * 4 + i];
        acc[i][0] += a * b4.x; acc[i][1] += a * b4.y;
        acc[i][2] += a * b4.z; acc[i][3] += a * b4.w;
      }
    }
    __syncthreads();
  }
#pragma unroll
  for (int i = 0; i < 4; ++i) {
    int r = bm + ty * 4 + i;
    if (r < s1) {
      int tok = ptok[r];
#pragma unroll
      for (int j = 0; j < 4; ++j)
        atomicAdd(&Cout[(size_t)tok * HDIM + bn + tx * 4 + j], acc[i][j]);
    }
  }
}

extern "C" void kernel_launch(void* const* d_in, const int* in_sizes, int n_in,
                              void* d_out, int out_size, void* d_ws, size_t ws_size,
                              hipStream_t stream) {
  const float* x        = (const float*)d_in[0];
  const int*   pos      = (const int*)d_in[1];
  const float* w_norm1  = (const float*)d_in[2];
  const float* wq       = (const float*)d_in[3];
  const float* wk       = (const float*)d_in[4];
  const float* wv       = (const float*)d_in[5];
  const float* wo       = (const float*)d_in[6];
  const float* w_norm2  = (const float*)d_in[7];
  const float* w_router = (const float*)d_in[8];
  const float* e_bias   = (const float*)d_in[9];
  const float* w_gate   = (const float*)d_in[10];
  const float* w_up     = (const float*)d_in[11];
  const float* w_down   = (const float*)d_in[12];
  const float* ws_gate  = (const float*)d_in[13];
  const float* ws_up    = (const float*)d_in[14];
  const float* ws_down  = (const float*)d_in[15];
  float* out = (float*)d_out;

  char* wp = (char*)d_ws;
  auto alloc = [&](size_t bytes) {
    void* p = (void*)wp;
    wp += (bytes + 255) & ~(size_t)255;
    return p;
  };
  float* hb    = (float*)alloc((size_t)S_LEN * HDIM * 4);       // h, later t
  float* qb    = (float*)alloc((size_t)S_LEN * HDIM * 4);
  float* kb    = (float*)alloc((size_t)S_LEN * NKV * DH * 4);
  float* vb    = (float*)alloc((size_t)S_LEN * NKV * DH * 4);
  float* ctx   = (float*)alloc((size_t)S_LEN * HDIM * 4);
  float* x2    = (float*)alloc((size_t)S_LEN * HDIM * 4);
  float* cos_t = (float*)alloc((size_t)S_LEN * 64 * 4);
  float* sin_t = (float*)alloc((size_t)S_LEN * 64 * 4);
  int*   sel   = (int*)alloc((size_t)S_LEN * 2 * 4);
  float* selw  = (float*)alloc((size_t)S_LEN * 2 * 4);
  int*   offs  = (int*)alloc((size_t)(NE + 1) * 4);
  int*   ptok  = (int*)alloc((size_t)S_LEN * 2 * 4);
  float* pw    = (float*)alloc((size_t)S_LEN * 2 * 4);
  float* g     = (float*)alloc((size_t)2 * S_LEN * IM * 4);
  float* u     = (float*)alloc((size_t)2 * S_LEN * IM * 4);
  float* act   = (float*)alloc((size_t)2 * S_LEN * IM * 4);
  float* sg    = (float*)alloc((size_t)S_LEN * IM * 4);
  float* su    = (float*)alloc((size_t)S_LEN * IM * 4);
  float* sact  = (float*)alloc((size_t)S_LEN * IM * 4);
  (void)ws_size; (void)n_in; (void)in_sizes; (void)out_size;

  // ---- attention block ----
  rmsnorm_k<<<S_LEN, 256, 0, stream>>>(x, w_norm1, hb);
  gemm_f32<<<dim3(HDIM / BN, S_LEN / BM), 256, 0, stream>>>(hb, wq, qb, nullptr, HDIM, HDIM);
  gemm_f32<<<dim3((NKV * DH) / BN, S_LEN / BM), 256, 0, stream>>>(hb, wk, kb, nullptr, NKV * DH, HDIM);
  gemm_f32<<<dim3((NKV * DH) / BN, S_LEN / BM), 256, 0, stream>>>(hb, wv, vb, nullptr, NKV * DH, HDIM);
  yarn_tables_k<<<S_LEN, 64, 0, stream>>>(pos, cos_t, sin_t);
  rope_k<<<S_LEN, 256, 0, stream>>>(qb, kb, cos_t, sin_t);
  attn_k<<<dim3(S_LEN, NH), 256, 0, stream>>>(qb, kb, vb, ctx);
  gemm_f32<<<dim3(HDIM / BN, S_LEN / BM), 256, 0, stream>>>(ctx, wo, x2, x, HDIM, HDIM);

  // ---- MoE block ----
  rmsnorm_k<<<S_LEN, 256, 0, stream>>>(x2, w_norm2, hb);  // hb = t
  router_k<<<S_LEN, 256, 0, stream>>>(hb, w_router, e_bias, sel, selw);
  group_k<<<1, 1024, 0, stream>>>(sel, selw, offs, ptok, pw);

  // shared expert: writes out = sact@ws_down + x2 (covers every element)
  gemm_f32<<<dim3(IM / BN, S_LEN / BM), 256, 0, stream>>>(hb, ws_gate, sg, nullptr, IM, HDIM);
  gemm_f32<<<dim3(IM / BN, S_LEN / BM), 256, 0, stream>>>(hb, ws_up, su, nullptr, IM, HDIM);
  act_mul_k<<<S_LEN, 256, 0, stream>>>(sg, su, nullptr, sact);
  gemm_f32<<<dim3(HDIM / BN, S_LEN / BM), 256, 0, stream>>>(sact, ws_down, out, x2, HDIM, IM);

  // routed experts (sparse, grouped); down accumulates atomically into out
  gemm_grouped_in<<<dim3(IM / BN, 16, NE), 256, 0, stream>>>(hb, w_gate, offs, ptok, g);
  gemm_grouped_in<<<dim3(IM / BN, 16, NE), 256, 0, stream>>>(hb, w_up, offs, ptok, u);
  act_mul_k<<<2 * S_LEN, 256, 0, stream>>>(g, u, pw, act);
  gemm_grouped_down<<<dim3(HDIM / BN, 16, NE), 256, 0, stream>>>(act, w_down, offs, ptok, out);
}

// Round 2
// 3999.335 us; speedup vs baseline: 1.3632x; 1.3632x over previous
//
#include <hip/hip_runtime.h>
#include <hip/hip_bf16.h>
#include <math.h>

#define S_LEN 1024
#define HDIM  4096
#define NH    32
#define NKV   8
#define DH    128
#define NE    8
#define IM    1280
#define QKVW  6144   // fused q|k|v row width

typedef __attribute__((ext_vector_type(8))) short bf16x8;
typedef __attribute__((ext_vector_type(4))) float f32x4;

__device__ __forceinline__ unsigned short f2bf(float x) {
  __hip_bfloat16 h = __float2bfloat16(x);
  return *reinterpret_cast<unsigned short*>(&h);
}

// ---------------- RMSNorm ----------------
__global__ __launch_bounds__(256) void rmsnorm_k(const float* __restrict__ x,
                                                 const float* __restrict__ w,
                                                 float* __restrict__ o) {
  int s = blockIdx.x, tid = threadIdx.x;
  const float* xr = x + (size_t)s * HDIM;
  float ss = 0.f;
  for (int i = tid; i < HDIM; i += 256) { float v = xr[i]; ss += v * v; }
  __shared__ float red[256];
  red[tid] = ss; __syncthreads();
  for (int off = 128; off > 0; off >>= 1) {
    if (tid < off) red[tid] += red[tid + off];
    __syncthreads();
  }
  float inv = rsqrtf(red[0] / (float)HDIM + 1e-5f);
  float* orow = o + (size_t)s * HDIM;
  for (int i = tid; i < HDIM; i += 256) orow[i] = xr[i] * inv * w[i];
}

// ---------------- fp32 GEMM: C[row, coff+col] = A[M,K]@B[K,Nb] (+R) ----------------
// 128x64 tile, 256 threads, 8x4 acc/thread (rows split ty*4 and 64+ty*4)
__global__ __launch_bounds__(256) void gemm_f32(const float* __restrict__ A,
                                                const float* __restrict__ B,
                                                float* __restrict__ C,
                                                const float* __restrict__ R,
                                                int Nb, int K, int ldc, int coff) {
  __shared__ float As[16][132];   // [k][m], 132*4B stride => 16B aligned, 2-way max
  __shared__ float Bs[16][68];
  int tid = threadIdx.x;
  int bm = blockIdx.y * 128, bn = blockIdx.x * 64;
  int ty = tid >> 4, tx = tid & 15;
  float acc[8][4] = {};
  int am = tid >> 2, ak0 = (tid & 3) * 4;
  int bk = tid >> 4, bn0 = (tid & 15) * 4;
  const float* Ap0 = A + (size_t)(bm + am) * K + ak0;
  const float* Ap1 = A + (size_t)(bm + 64 + am) * K + ak0;
  const float* Bp  = B + (size_t)bk * Nb + bn + bn0;
  for (int kt = 0; kt < K; kt += 16) {
    float4 a0 = *(const float4*)(Ap0 + kt);
    float4 a1 = *(const float4*)(Ap1 + kt);
    float4 bv = *(const float4*)(Bp + (size_t)kt * Nb);
    As[ak0 + 0][am] = a0.x; As[ak0 + 1][am] = a0.y;
    As[ak0 + 2][am] = a0.z; As[ak0 + 3][am] = a0.w;
    As[ak0 + 0][64 + am] = a1.x; As[ak0 + 1][64 + am] = a1.y;
    As[ak0 + 2][64 + am] = a1.z; As[ak0 + 3][64 + am] = a1.w;
    *(float4*)&Bs[bk][bn0] = bv;
    __syncthreads();
#pragma unroll
    for (int kk = 0; kk < 16; ++kk) {
      float4 x0 = *(const float4*)&As[kk][ty * 4];
      float4 x1 = *(const float4*)&As[kk][64 + ty * 4];
      float4 bb = *(const float4*)&Bs[kk][tx * 4];
      float xa[8] = {x0.x, x0.y, x0.z, x0.w, x1.x, x1.y, x1.z, x1.w};
      float bbv[4] = {bb.x, bb.y, bb.z, bb.w};
#pragma unroll
      for (int i = 0; i < 8; ++i)
#pragma unroll
        for (int j = 0; j < 4; ++j) acc[i][j] += xa[i] * bbv[j];
    }
    __syncthreads();
  }
#pragma unroll
  for (int half = 0; half < 2; ++half)
#pragma unroll
    for (int i = 0; i < 4; ++i) {
      int row = bm + half * 64 + ty * 4 + i;
      size_t base = (size_t)row * ldc + coff + bn + tx * 4;
      float4 v;
      v.x = acc[half * 4 + i][0]; v.y = acc[half * 4 + i][1];
      v.z = acc[half * 4 + i][2]; v.w = acc[half * 4 + i][3];
      if (R) {
        float4 rv = *(const float4*)(R + base);
        v.x += rv.x; v.y += rv.y; v.z += rv.z; v.w += rv.w;
      }
      *(float4*)(C + base) = v;
    }
}

// ---------------- YaRN cos/sin tables ----------------
__global__ void yarn_tables_k(const int* __restrict__ pos_ids,
                              float* __restrict__ cos_t, float* __restrict__ sin_t) {
  int s = blockIdx.x, d = threadIdx.x;  // d in [0,64)
  const double TWO_PI = 6.283185307179586476925286766559;
  double inv = pow(1.0e6, -((double)(2 * d)) / 128.0);
  double lnb = log(1.0e6);
  double low = floor(64.0 * log(65536.0 / (32.0 * TWO_PI)) / lnb);
  if (low < 0.0) low = 0.0;
  double high = ceil(64.0 * log(65536.0 / (1.0 * TWO_PI)) / lnb);
  if (high > 127.0) high = 127.0;
  double ramp = ((double)d - low) / (high - low);
  ramp = fmin(fmax(ramp, 0.0), 1.0);
  double extra = 1.0 - ramp;
  double inv_y = (inv / 2.0) * (1.0 - extra) + inv * extra;
  float invf = (float)inv_y;
  float p = (float)pos_ids[s];
  float ang = p * invf;
  const float scal = 1.0693147180559945f;
  cos_t[s * 64 + d] = cosf(ang) * scal;
  sin_t[s * 64 + d] = sinf(ang) * scal;
}

// ---------------- RoPE (in place on fused qkv) ----------------
__global__ __launch_bounds__(256) void rope_k(float* __restrict__ qkv,
                                              const float* __restrict__ cos_t,
                                              const float* __restrict__ sin_t) {
  int s = blockIdx.x, tid = threadIdx.x;
  const float* ct = cos_t + (size_t)s * 64;
  const float* st = sin_t + (size_t)s * 64;
  float* row = qkv + (size_t)s * QKVW;
  for (int i = tid; i < NH * 64; i += 256) {
    int h = i >> 6, d = i & 63;
    float* base = row + h * DH;
    float q1 = base[d], q2 = base[d + 64];
    float c = ct[d], sn = st[d];
    base[d] = q1 * c - q2 * sn;
    base[d + 64] = q2 * c + q1 * sn;
  }
  for (int i = tid; i < NKV * 64; i += 256) {
    int h = i >> 6, d = i & 63;
    float* base = row + HDIM + h * DH;
    float q1 = base[d], q2 = base[d + 64];
    float c = ct[d], sn = st[d];
    base[d] = q1 * c - q2 * sn;
    base[d + 64] = q2 * c + q1 * sn;
  }
}

// ---------------- flash attention: block = (head, 64-row q-tile) ----------------
#define FA_M 64
#define FA_NK 32
__global__ __launch_bounds__(256) void fattn_k(const float* __restrict__ qkv,
                                               float* __restrict__ O) {
  int b = blockIdx.x;
  int h = b >> 4;
  int ii = b & 15;
  int qt = (ii & 1) ? (15 - (ii >> 1)) : (ii >> 1);  // pair heavy+light tiles
  int kvh = h >> 2;
  int q0 = qt * FA_M;
  int tid = threadIdx.x;
  int ty = tid >> 4, tx = tid & 15;

  __shared__ float Qs[DH][FA_M];    // Q^T, 32 KB
  __shared__ float KV[DH * FA_NK];  // K^T then V, 16 KB
  __shared__ float Ps[FA_NK][FA_M]; // P^T, 8 KB

  {  // stage Q transposed (lane-per-row: conflict-free LDS writes)
    int r = tid & 63;
    int c4b = tid >> 6;
    const float* qrow = qkv + (size_t)(q0 + r) * QKVW + h * DH;
#pragma unroll
    for (int it = 0; it < 8; ++it) {
      int c4 = it * 4 + c4b;
      float4 v = *(const float4*)(qrow + c4 * 4);
      Qs[c4 * 4 + 0][r] = v.x; Qs[c4 * 4 + 1][r] = v.y;
      Qs[c4 * 4 + 2][r] = v.z; Qs[c4 * 4 + 3][r] = v.w;
    }
  }
  float m_i[4] = {-1e30f, -1e30f, -1e30f, -1e30f};
  float l_i[4] = {0.f, 0.f, 0.f, 0.f};
  float Oacc[4][8] = {};
  __syncthreads();

  const float scale = 0.08838834764831845f;  // 1/sqrt(128)
  int ntiles = 2 * qt + 2;
  for (int t = 0; t < ntiles; ++t) {
    int c0 = t * FA_NK;
    {  // stage K transposed
      int kr = tid & 31;
      int c4b = tid >> 5;
      const float* krow = qkv + (size_t)(c0 + kr) * QKVW + HDIM + kvh * DH;
#pragma unroll
      for (int it = 0; it < 4; ++it) {
        int c4 = it * 8 + c4b;
        float4 v = *(const float4*)(krow + c4 * 4);
        KV[(c4 * 4 + 0) * FA_NK + kr] = v.x;
        KV[(c4 * 4 + 1) * FA_NK + kr] = v.y;
        KV[(c4 * 4 + 2) * FA_NK + kr] = v.z;
        KV[(c4 * 4 + 3) * FA_NK + kr] = v.w;
      }
    }
    __syncthreads();
    float sacc[4][2] = {};
#pragma unroll 2
    for (int d = 0; d < DH; ++d) {
      float4 qv = *(const float4*)&Qs[d][ty * 4];
      float2 kv2 = *(const float2*)&KV[d * FA_NK + tx * 2];
      float qa[4] = {qv.x, qv.y, qv.z, qv.w};
#pragma unroll
      for (int i = 0; i < 4; ++i) {
        sacc[i][0] += qa[i] * kv2.x;
        sacc[i][1] += qa[i] * kv2.y;
      }
    }
    float al[4];
#pragma unroll
    for (int i = 0; i < 4; ++i) {
      int rg = q0 + ty * 4 + i;
      float s0v = (c0 + tx * 2 + 0 > rg) ? -1e30f : sacc[i][0] * scale;
      float s1v = (c0 + tx * 2 + 1 > rg) ? -1e30f : sacc[i][1] * scale;
      float tm = fmaxf(s0v, s1v);
      for (int o = 8; o >= 1; o >>= 1) tm = fmaxf(tm, __shfl_xor(tm, o, 16));
      float newm = fmaxf(m_i[i], tm);
      float a = expf(m_i[i] - newm);
      float p0 = expf(s0v - newm), p1 = expf(s1v - newm);
      float ts = p0 + p1;
      for (int o = 8; o >= 1; o >>= 1) ts += __shfl_xor(ts, o, 16);
      l_i[i] = l_i[i] * a + ts;
      m_i[i] = newm;
      al[i] = a;
      Ps[tx * 2 + 0][ty * 4 + i] = p0;
      Ps[tx * 2 + 1][ty * 4 + i] = p1;
    }
#pragma unroll
    for (int i = 0; i < 4; ++i)
#pragma unroll
      for (int jj = 0; jj < 8; ++jj) Oacc[i][jj] *= al[i];
    __syncthreads();
    {  // stage V natural layout
      int vd0 = (tid & 31) * 4;
      int vkb = tid >> 5;
#pragma unroll
      for (int it = 0; it < 4; ++it) {
        int vk = it * 8 + vkb;
        float4 v = *(const float4*)(qkv + (size_t)(c0 + vk) * QKVW + HDIM + NKV * DH + kvh * DH + vd0);
        *(float4*)&KV[vk * DH + vd0] = v;
      }
    }
    __syncthreads();
#pragma unroll 4
    for (int k = 0; k < FA_NK; ++k) {
      float4 p4 = *(const float4*)&Ps[k][ty * 4];
      float4 v0 = *(const float4*)&KV[k * DH + tx * 4];
      float4 v1 = *(const float4*)&KV[k * DH + 64 + tx * 4];
      float pa[4] = {p4.x, p4.y, p4.z, p4.w};
      float va[8] = {v0.x, v0.y, v0.z, v0.w, v1.x, v1.y, v1.z, v1.w};
#pragma unroll
      for (int i = 0; i < 4; ++i)
#pragma unroll
        for (int jj = 0; jj < 8; ++jj) Oacc[i][jj] += pa[i] * va[jj];
    }
    __syncthreads();
  }
#pragma unroll
  for (int i = 0; i < 4; ++i) {
    float inv = 1.0f / l_i[i];
    float* orow = O + (size_t)(q0 + ty * 4 + i) * HDIM + h * DH;
    float4 v0, v1;
    v0.x = Oacc[i][0] * inv; v0.y = Oacc[i][1] * inv;
    v0.z = Oacc[i][2] * inv; v0.w = Oacc[i][3] * inv;
    v1.x = Oacc[i][4] * inv; v1.y = Oacc[i][5] * inv;
    v1.z = Oacc[i][6] * inv; v1.w = Oacc[i][7] * inv;
    *(float4*)(orow + tx * 4) = v0;
    *(float4*)(orow + 64 + tx * 4) = v1;
  }
}

// ---------------- router (fp32 exact path) ----------------
__global__ __launch_bounds__(256) void router_k(const float* __restrict__ T,
                                                const float* __restrict__ wr,
                                                const float* __restrict__ eb,
                                                int* __restrict__ sel,
                                                float* __restrict__ selw) {
  int s = blockIdx.x, tid = threadIdx.x;
  int e = tid & 7, c = tid >> 3;
  const float* tr = T + (size_t)s * HDIM;
  float p = 0.f;
  for (int hh = c * 128; hh < (c + 1) * 128; ++hh) p += tr[hh] * wr[hh * NE + e];
  __shared__ float red[256];
  red[tid] = p; __syncthreads();
  for (int off = 128; off >= 8; off >>= 1) {
    if (tid < off) red[tid] += red[tid + off];
    __syncthreads();
  }
  if (tid == 0) {
    float sg[NE], bb[NE];
    for (int i = 0; i < NE; ++i) { sg[i] = 1.f / (1.f + expf(-red[i])); bb[i] = sg[i] + eb[i]; }
    int i0 = 0;
    for (int i = 1; i < NE; ++i) if (bb[i] > bb[i0]) i0 = i;
    int i1 = -1;
    for (int i = 0; i < NE; ++i) if (i != i0 && (i1 < 0 || bb[i] > bb[i1])) i1 = i;
    float w0 = sg[i0], w1 = sg[i1], ws = w0 + w1;
    sel[s * 2] = i0; sel[s * 2 + 1] = i1;
    selw[s * 2] = w0 / ws; selw[s * 2 + 1] = w1 / ws;
  }
}

// ---------------- group (token,slot) pairs by expert ----------------
__global__ __launch_bounds__(1024) void group_k(const int* __restrict__ sel,
                                                const float* __restrict__ selw,
                                                int* __restrict__ offs,
                                                int* __restrict__ ptok,
                                                float* __restrict__ pw) {
  __shared__ int cnt[NE], base[NE], cur[NE];
  int t = threadIdx.x;
  if (t < NE) { cnt[t] = 0; cur[t] = 0; }
  __syncthreads();
  int e0 = sel[t * 2], e1 = sel[t * 2 + 1];
  atomicAdd(&cnt[e0], 1); atomicAdd(&cnt[e1], 1);
  __syncthreads();
  if (t == 0) {
    int a = 0;
    for (int e = 0; e < NE; ++e) { base[e] = a; offs[e] = a; a += cnt[e]; }
    offs[NE] = a;
  }
  __syncthreads();
  int p0 = base[e0] + atomicAdd(&cur[e0], 1);
  ptok[p0] = t; pw[p0] = selw[t * 2];
  int p1 = base[e1] + atomicAdd(&cur[e1], 1);
  ptok[p1] = t; pw[p1] = selw[t * 2 + 1];
}

// ---------------- bf16 MFMA GEMM (gate/up): C = A(fp32,rows via ptok?) @ B(fp32) ----------------
// 128x128 tile, 256 thr, in-staging fp32->bf16 convert. A[?,K] row-major, B[K,N] row-major.
__global__ __launch_bounds__(256) void mfma_gateup_k(const float* __restrict__ Ab,
                                                     const float* __restrict__ Bb,
                                                     float* __restrict__ C,
                                                     const int* __restrict__ offs,
                                                     const int* __restrict__ ptok,
                                                     int N, int K, int Mdense) {
  int e = blockIdx.z;
  int s0 = 0, s1 = Mdense;
  if (offs) { s0 = offs[e]; s1 = offs[e + 1]; }
  int bm = s0 + blockIdx.y * 128;
  if (bm >= s1) return;
  int bn = blockIdx.x * 128;
  const float* B = Bb + (size_t)e * K * N;
  __shared__ unsigned short As[128][40];   // stride 80B: 16B-aligned frags, ~2-way reads
  __shared__ unsigned short Bs[128][40];
  int tid = threadIdx.x;
  int lane = tid & 63, wave = tid >> 6;
  int wm = wave >> 1, wn = wave & 1;
  int quad = lane >> 4, l15 = lane & 15;
  f32x4 acc[4][4];
  for (int i = 0; i < 4; ++i)
    for (int j = 0; j < 4; ++j)
      for (int r = 0; r < 4; ++r) acc[i][j][r] = 0.f;

  const float* aptr[4]; bool aval[4]; int amv[4], ak0v[4];
#pragma unroll
  for (int g2 = 0; g2 < 4; ++g2) {
    int chunk = g2 * 256 + tid;
    int am = chunk >> 3, ak0 = (chunk & 7) * 4;
    int row = bm + am;
    bool v = row < s1;
    int arow = v ? (ptok ? ptok[row] : row) : 0;
    aptr[g2] = Ab + (size_t)arow * K + ak0;
    aval[g2] = v; amv[g2] = am; ak0v[g2] = ak0;
  }
  int bnl = tid & 127, bkq = (tid >> 7) * 4;
  const float* bcol = B + bn + bnl;

  for (int kt = 0; kt < K; kt += 32) {
#pragma unroll
    for (int g2 = 0; g2 < 4; ++g2) {
      float4 v = aval[g2] ? *(const float4*)(aptr[g2] + kt) : make_float4(0.f, 0.f, 0.f, 0.f);
      ushort4 pk;
      pk.x = f2bf(v.x); pk.y = f2bf(v.y); pk.z = f2bf(v.z); pk.w = f2bf(v.w);
      *(ushort4*)&As[amv[g2]][ak0v[g2]] = pk;
    }
#pragma unroll
    for (int it = 0; it < 4; ++it) {
      int kb = it * 8 + bkq;
      const float* bp = bcol + (size_t)(kt + kb) * N;
      float b0 = bp[0], b1 = bp[N], b2 = bp[2 * (size_t)N], b3 = bp[3 * (size_t)N];
      ushort4 pk;
      pk.x = f2bf(b0); pk.y = f2bf(b1); pk.z = f2bf(b2); pk.w = f2bf(b3);
      *(ushort4*)&Bs[bnl][kb] = pk;
    }
    __syncthreads();
    bf16x8 af[4], bfr[4];
#pragma unroll
    for (int t2 = 0; t2 < 4; ++t2) {
      af[t2] = *(const bf16x8*)&As[wm * 64 + t2 * 16 + l15][quad * 8];
      bfr[t2] = *(const bf16x8*)&Bs[wn * 64 + t2 * 16 + l15][quad * 8];
    }
#pragma unroll
    for (int i = 0; i < 4; ++i)
#pragma unroll
      for (int j = 0; j < 4; ++j)
        acc[i][j] = __builtin_amdgcn_mfma_f32_16x16x32_bf16(af[i], bfr[j], acc[i][j], 0, 0, 0);
    __syncthreads();
  }
#pragma unroll
  for (int i = 0; i < 4; ++i)
#pragma unroll
    for (int j = 0; j < 4; ++j)
#pragma unroll
      for (int r = 0; r < 4; ++r) {
        int grow = bm + wm * 64 + i * 16 + quad * 4 + r;
        if (grow < s1) {
          int gcol = bn + wn * 64 + j * 16 + l15;
          C[(size_t)grow * N + gcol] = acc[i][j][r];
        }
      }
}

// ---------------- bf16 MFMA down GEMM: A bf16 [rows][K], B fp32 [K][N] ----------------
// Rres != null: dense store out = acc + Rres. Else: atomicAdd to out[ptok[row]].
__global__ __launch_bounds__(256) void mfma_down_k(const unsigned short* __restrict__ Ab,
                                                   const float* __restrict__ Bb,
                                                   float* __restrict__ Cout,
                                                   const float* __restrict__ Rres,
                                                   const int* __restrict__ offs,
                                                   const int* __restrict__ ptok,
                                                   int N, int K, int Mdense) {
  int e = blockIdx.z;
  int s0 = 0, s1 = Mdense;
  if (offs) { s0 = offs[e]; s1 = offs[e + 1]; }
  int bm = s0 + blockIdx.y * 128;
  if (bm >= s1) return;
  int bn = blockIdx.x * 128;
  const float* B = Bb + (size_t)e * K * N;
  __shared__ unsigned short As[128][40];
  __shared__ unsigned short Bs[128][40];
  int tid = threadIdx.x;
  int lane = tid & 63, wave = tid >> 6;
  int wm = wave >> 1, wn = wave & 1;
  int quad = lane >> 4, l15 = lane & 15;
  f32x4 acc[4][4];
  for (int i = 0; i < 4; ++i)
    for (int j = 0; j < 4; ++j)
      for (int r = 0; r < 4; ++r) acc[i][j][r] = 0.f;

  const unsigned short* aptr[2]; bool aval[2]; int amv[2], ak0v[2];
#pragma unroll
  for (int g2 = 0; g2 < 2; ++g2) {
    int chunk = g2 * 256 + tid;
    int am = chunk >> 2, ak0 = (chunk & 3) * 8;
    int row = bm + am;
    bool v = row < s1;
    aptr[g2] = Ab + (size_t)(v ? row : 0) * K + ak0;
    aval[g2] = v; amv[g2] = am; ak0v[g2] = ak0;
  }
  int bnl = tid & 127, bkq = (tid >> 7) * 4;
  const float* bcol = B + bn + bnl;

  for (int kt = 0; kt < K; kt += 32) {
#pragma unroll
    for (int g2 = 0; g2 < 2; ++g2) {
      float4 v = make_float4(0.f, 0.f, 0.f, 0.f);
      if (aval[g2]) v = *(const float4*)(aptr[g2] + kt);  // 8 bf16
      *(float4*)&As[amv[g2]][ak0v[g2]] = v;
    }
#pragma unroll
    for (int it = 0; it < 4; ++it) {
      int kb = it * 8 + bkq;
      const float* bp = bcol + (size_t)(kt + kb) * N;
      float b0 = bp[0], b1 = bp[N], b2 = bp[2 * (size_t)N], b3 = bp[3 * (size_t)N];
      ushort4 pk;
      pk.x = f2bf(b0); pk.y = f2bf(b1); pk.z = f2bf(b2); pk.w = f2bf(b3);
      *(ushort4*)&Bs[bnl][kb] = pk;
    }
    __syncthreads();
    bf16x8 af[4], bfr[4];
#pragma unroll
    for (int t2 = 0; t2 < 4; ++t2) {
      af[t2] = *(const bf16x8*)&As[wm * 64 + t2 * 16 + l15][quad * 8];
      bfr[t2] = *(const bf16x8*)&Bs[wn * 64 + t2 * 16 + l15][quad * 8];
    }
#pragma unroll
    for (int i = 0; i < 4; ++i)
#pragma unroll
      for (int j = 0; j < 4; ++j)
        acc[i][j] = __builtin_amdgcn_mfma_f32_16x16x32_bf16(af[i], bfr[j], acc[i][j], 0, 0, 0);
    __syncthreads();
  }
#pragma unroll
  for (int i = 0; i < 4; ++i)
#pragma unroll
    for (int j = 0; j < 4; ++j)
#pragma unroll
      for (int r = 0; r < 4; ++r) {
        int grow = bm + wm * 64 + i * 16 + quad * 4 + r;
        if (grow < s1) {
          int gcol = bn + wn * 64 + j * 16 + l15;
          if (Rres) {
            Cout[(size_t)grow * N + gcol] = acc[i][j][r] + Rres[(size_t)grow * N + gcol];
          } else {
            atomicAdd(&Cout[(size_t)ptok[grow] * N + gcol], acc[i][j][r]);
          }
        }
      }
}

// ---------------- silu(g)*u*w -> bf16 ----------------
__global__ __launch_bounds__(256) void act_mul_bf16_k(const float* __restrict__ g,
                                                      const float* __restrict__ u,
                                                      const float* __restrict__ pw,
                                                      unsigned short* __restrict__ a) {
  int r = blockIdx.x, tid = threadIdx.x;
  float wgt = pw ? pw[r] : 1.f;
  size_t bse = (size_t)r * IM;
  for (int i = tid; i < IM; i += 256) {
    float gv = g[bse + i], uv = u[bse + i];
    float sv = gv / (1.f + expf(-gv));
    a[bse + i] = f2bf(sv * uv * wgt);
  }
}

extern "C" void kernel_launch(void* const* d_in, const int* in_sizes, int n_in,
                              void* d_out, int out_size, void* d_ws, size_t ws_size,
                              hipStream_t stream) {
  const float* x        = (const float*)d_in[0];
  const int*   pos      = (const int*)d_in[1];
  const float* w_norm1  = (const float*)d_in[2];
  const float* wq       = (const float*)d_in[3];
  const float* wk       = (const float*)d_in[4];
  const float* wv       = (const float*)d_in[5];
  const float* wo       = (const float*)d_in[6];
  const float* w_norm2  = (const float*)d_in[7];
  const float* w_router = (const float*)d_in[8];
  const float* e_bias   = (const float*)d_in[9];
  const float* w_gate   = (const float*)d_in[10];
  const float* w_up     = (const float*)d_in[11];
  const float* w_down   = (const float*)d_in[12];
  const float* ws_gate  = (const float*)d_in[13];
  const float* ws_up    = (const float*)d_in[14];
  const float* ws_down  = (const float*)d_in[15];
  float* out = (float*)d_out;

  char* wp = (char*)d_ws;
  auto alloc = [&](size_t bytes) {
    void* p = (void*)wp;
    wp += (bytes + 255) & ~(size_t)255;
    return p;
  };
  float* qkv   = (float*)alloc((size_t)S_LEN * QKVW * 4);       // also reused for g,u
  float* hb    = (float*)alloc((size_t)S_LEN * HDIM * 4);
  float* ctx   = (float*)alloc((size_t)S_LEN * HDIM * 4);       // also reused for sg,su
  float* x2    = (float*)alloc((size_t)S_LEN * HDIM * 4);
  float* cos_t = (float*)alloc((size_t)S_LEN * 64 * 4);
  float* sin_t = (float*)alloc((size_t)S_LEN * 64 * 4);
  int*   sel   = (int*)alloc((size_t)S_LEN * 2 * 4);
  float* selw  = (float*)alloc((size_t)S_LEN * 2 * 4);
  int*   offs  = (int*)alloc((size_t)(NE + 1) * 4);
  int*   ptok  = (int*)alloc((size_t)S_LEN * 2 * 4);
  float* pw    = (float*)alloc((size_t)S_LEN * 2 * 4);
  unsigned short* sact = (unsigned short*)alloc((size_t)S_LEN * IM * 2);
  unsigned short* act  = (unsigned short*)alloc((size_t)2 * S_LEN * IM * 2);
  // aliases into dead buffers
  float* g  = qkv;                                   // qkv dead after attention
  float* u  = qkv + (size_t)2 * S_LEN * IM;
  float* sg = ctx;                                   // ctx dead after wo-gemm
  float* su = ctx + (size_t)S_LEN * IM;
  (void)ws_size; (void)n_in; (void)in_sizes; (void)out_size;

  // ---- attention block ----
  rmsnorm_k<<<S_LEN, 256, 0, stream>>>(x, w_norm1, hb);
  gemm_f32<<<dim3(64, 8), 256, 0, stream>>>(hb, wq, qkv, nullptr, 4096, 4096, QKVW, 0);
  gemm_f32<<<dim3(16, 8), 256, 0, stream>>>(hb, wk, qkv, nullptr, 1024, 4096, QKVW, 4096);
  gemm_f32<<<dim3(16, 8), 256, 0, stream>>>(hb, wv, qkv, nullptr, 1024, 4096, QKVW, 5120);
  yarn_tables_k<<<S_LEN, 64, 0, stream>>>(pos, cos_t, sin_t);
  rope_k<<<S_LEN, 256, 0, stream>>>(qkv, cos_t, sin_t);
  fattn_k<<<512, 256, 0, stream>>>(qkv, ctx);
  gemm_f32<<<dim3(64, 8), 256, 0, stream>>>(ctx, wo, x2, x, 4096, 4096, 4096, 0);

  // ---- MoE block ----
  rmsnorm_k<<<S_LEN, 256, 0, stream>>>(x2, w_norm2, hb);
  router_k<<<S_LEN, 256, 0, stream>>>(hb, w_router, e_bias, sel, selw);
  group_k<<<1, 1024, 0, stream>>>(sel, selw, offs, ptok, pw);

  // shared expert (dense): out = silu(h@wsg)*(h@wsu) @ wsd + x2
  mfma_gateup_k<<<dim3(10, 8, 1), 256, 0, stream>>>(hb, ws_gate, sg, nullptr, nullptr, IM, HDIM, S_LEN);
  mfma_gateup_k<<<dim3(10, 8, 1), 256, 0, stream>>>(hb, ws_up, su, nullptr, nullptr, IM, HDIM, S_LEN);
  act_mul_bf16_k<<<S_LEN, 256, 0, stream>>>(sg, su, nullptr, sact);
  mfma_down_k<<<dim3(32, 8, 1), 256, 0, stream>>>(sact, ws_down, out, x2, nullptr, nullptr, HDIM, IM, S_LEN);

  // routed experts (grouped, post-selection => bf16 safe)
  mfma_gateup_k<<<dim3(10, 16, NE), 256, 0, stream>>>(hb, w_gate, g, offs, ptok, IM, HDIM, 0);
  mfma_gateup_k<<<dim3(10, 16, NE), 256, 0, stream>>>(hb, w_up, u, offs, ptok, IM, HDIM, 0);
  act_mul_bf16_k<<<2 * S_LEN, 256, 0, stream>>>(g, u, pw, act);
  mfma_down_k<<<dim3(32, 16, NE), 256, 0, stream>>>(act, w_down, out, nullptr, offs, ptok, HDIM, IM, 0);
}